// Round 1
// baseline (108.059 us; speedup 1.0000x reference)
//
#include <hip/hip_runtime.h>
#include <math.h>

#define BLOCK 256
#define NRPT 4          // rays per thread -> float4-aligned I/O, 4-way ILP
#define HIDDEN_ 128
#define MAXIT 64

__global__ __launch_bounds__(BLOCK) void sphere_trace_kernel(
    const float* __restrict__ origins,
    const float* __restrict__ directions,
    const float* __restrict__ center,
    const float* __restrict__ radius,
    const float* __restrict__ W1,
    const float* __restrict__ b1,
    const float* __restrict__ W2,
    const float* __restrict__ b2,
    float* __restrict__ out,
    int nray)
{
    // Repacked weights: [j][0] = {W1[0][j], W1[1][j], W1[2][j], b1[j]}
    //                   [j][1] = {W2[j][0], W2[j][1], W2[j][2], 0}
    __shared__ float4 wlds[HIDDEN_][2];

    const int tid = threadIdx.x;
    if (tid < HIDDEN_) {
        const int j = tid;
        float4 a;
        a.x = W1[j];
        a.y = W1[HIDDEN_ + j];
        a.z = W1[2 * HIDDEN_ + j];
        a.w = b1[j];
        float4 b;
        b.x = W2[3 * j + 0];
        b.y = W2[3 * j + 1];
        b.z = W2[3 * j + 2];
        b.w = 0.0f;
        wlds[j][0] = a;
        wlds[j][1] = b;
    }

    const float cx = center[0], cy = center[1], cz = center[2];
    const float rad = radius[0];
    const float bo0 = b2[0], bo1 = b2[1], bo2 = b2[2];

    __syncthreads();

    const int base = (blockIdx.x * BLOCK + tid) * NRPT;
    if (base >= nray) return;

    const float4* o4 = reinterpret_cast<const float4*>(origins + 3 * (size_t)base);
    const float4* d4 = reinterpret_cast<const float4*>(directions + 3 * (size_t)base);
    const float4 oA = o4[0], oB = o4[1], oC = o4[2];
    const float4 dA = d4[0], dB = d4[1], dC = d4[2];

    float qx[NRPT], qy[NRPT], qz[NRPT];   // q = p - center
    float dx[NRPT], dy[NRPT], dz[NRPT];

    qx[0] = oA.x - cx; qy[0] = oA.y - cy; qz[0] = oA.z - cz;
    qx[1] = oA.w - cx; qy[1] = oB.x - cy; qz[1] = oB.y - cz;
    qx[2] = oB.z - cx; qy[2] = oB.w - cy; qz[2] = oC.x - cz;
    qx[3] = oC.y - cx; qy[3] = oC.z - cy; qz[3] = oC.w - cz;

    dx[0] = dA.x; dy[0] = dA.y; dz[0] = dA.z;
    dx[1] = dA.w; dy[1] = dB.x; dz[1] = dB.y;
    dx[2] = dB.z; dy[2] = dB.w; dz[2] = dC.x;
    dx[3] = dC.y; dy[3] = dC.z; dz[3] = dC.w;

    float slast[NRPT];
#pragma unroll
    for (int r = 0; r < NRPT; ++r) slast[r] = 0.0f;

    // Sphere tracing. Mask uses the sdf computed BEFORE the last update
    // (i.e. the s of the final executed iteration). Wave-uniform early exit
    // every 4 iters: converged (s<1e-5, monotone decreasing -> mask bit
    // unchanged, residual movement <= 64e-5) or diverged (s>1e6 / NaN ->
    // masked to 0 anyway).
    for (int ob = 0; ob < MAXIT / 4; ++ob) {
#pragma unroll
        for (int ii = 0; ii < 4; ++ii) {
#pragma unroll
            for (int r = 0; r < NRPT; ++r) {
                float f = qx[r] * qx[r];
                f = fmaf(qy[r], qy[r], f);
                f = fmaf(qz[r], qz[r], f);
                const float s = __builtin_amdgcn_sqrtf(f) - rad;
                qx[r] = fmaf(s, dx[r], qx[r]);
                qy[r] = fmaf(s, dy[r], qy[r]);
                qz[r] = fmaf(s, dz[r], qz[r]);
                slast[r] = s;
            }
        }
        bool done = true;
#pragma unroll
        for (int r = 0; r < NRPT; ++r) {
            const float s = slast[r];
            done = done && ((s < 1e-5f) || (s > 1e6f) || !(s == s));
        }
        if (__all(done)) break;
    }

    // Fused MLP: col = sigmoid(relu(p@W1+b1)@W2+b2), never materialize h[128].
    float px[NRPT], py[NRPT], pz[NRPT];
    float a0[NRPT], a1[NRPT], a2[NRPT];
#pragma unroll
    for (int r = 0; r < NRPT; ++r) {
        px[r] = qx[r] + cx;
        py[r] = qy[r] + cy;
        pz[r] = qz[r] + cz;
        a0[r] = bo0; a1[r] = bo1; a2[r] = bo2;
    }

#pragma unroll 2
    for (int j = 0; j < HIDDEN_; ++j) {
        const float4 w = wlds[j][0];   // broadcast ds_read_b128, conflict-free
        const float4 v = wlds[j][1];
#pragma unroll
        for (int r = 0; r < NRPT; ++r) {
            float h = fmaf(px[r], w.x, fmaf(py[r], w.y, fmaf(pz[r], w.z, w.w)));
            h = fmaxf(h, 0.0f);
            a0[r] = fmaf(h, v.x, a0[r]);
            a1[r] = fmaf(h, v.y, a1[r]);
            a2[r] = fmaf(h, v.z, a2[r]);
        }
    }

    float colv[NRPT][3];
#pragma unroll
    for (int r = 0; r < NRPT; ++r) {
        const bool hit = slast[r] < 0.0001f;   // matches reference SDF_EPS compare
        const float c0 = __builtin_amdgcn_rcpf(1.0f + __expf(-a0[r]));
        const float c1 = __builtin_amdgcn_rcpf(1.0f + __expf(-a1[r]));
        const float c2 = __builtin_amdgcn_rcpf(1.0f + __expf(-a2[r]));
        colv[r][0] = hit ? c0 : 0.0f;   // select, not multiply: kills NaN/inf
        colv[r][1] = hit ? c1 : 0.0f;
        colv[r][2] = hit ? c2 : 0.0f;
    }

    float4* ov = reinterpret_cast<float4*>(out + 3 * (size_t)base);
    ov[0] = make_float4(colv[0][0], colv[0][1], colv[0][2], colv[1][0]);
    ov[1] = make_float4(colv[1][1], colv[1][2], colv[2][0], colv[2][1]);
    ov[2] = make_float4(colv[2][2], colv[3][0], colv[3][1], colv[3][2]);
}

extern "C" void kernel_launch(void* const* d_in, const int* in_sizes, int n_in,
                              void* d_out, int out_size, void* d_ws, size_t ws_size,
                              hipStream_t stream) {
    const float* origins    = (const float*)d_in[0];
    const float* directions = (const float*)d_in[1];
    const float* center     = (const float*)d_in[2];
    const float* radius     = (const float*)d_in[3];
    const float* W1         = (const float*)d_in[4];
    const float* b1         = (const float*)d_in[5];
    const float* W2         = (const float*)d_in[6];
    const float* b2         = (const float*)d_in[7];
    float* out = (float*)d_out;

    const int nray = in_sizes[0] / 3;
    const int blocks = (nray + BLOCK * NRPT - 1) / (BLOCK * NRPT);
    sphere_trace_kernel<<<blocks, BLOCK, 0, stream>>>(
        origins, directions, center, radius, W1, b1, W2, b2, out, nray);
}